// Round 8
// baseline (447.551 us; speedup 1.0000x reference)
//
#include <hip/hip_runtime.h>
#include <hip/hip_bf16.h>

#define HID 256
#define NROWS 2048
#define GRID (NROWS / 8)        // 256 blocks x 512 threads; 8 waves, 1 n-row/wave

typedef __attribute__((ext_vector_type(8))) short short8;   // 8 bf16 (MFMA A/B frag)
typedef __attribute__((ext_vector_type(4))) float float4v;
typedef __attribute__((ext_vector_type(4))) unsigned int uint4v;

__device__ __forceinline__ unsigned int pk_bf16(float a, float b) {
    __hip_bfloat162 p = __float22bfloat162_rn(float2{a, b});  // v_cvt_pk_bf16_f32
    return *(unsigned int*)&p;
}

// sum across each 16-lane DPP row (VALU pipe, no LDS)
__device__ __forceinline__ float row16_sum(float v) {
    float t;
    t = __builtin_bit_cast(float, __builtin_amdgcn_update_dpp(
            0, __builtin_bit_cast(int, v), 0xB1, 0xf, 0xf, true));  // quad_perm(1,0,3,2)
    v += t;
    t = __builtin_bit_cast(float, __builtin_amdgcn_update_dpp(
            0, __builtin_bit_cast(int, v), 0x4E, 0xf, 0xf, true));  // quad_perm(2,3,0,1)
    v += t;
    t = __builtin_bit_cast(float, __builtin_amdgcn_update_dpp(
            0, __builtin_bit_cast(int, v), 0x124, 0xf, 0xf, true)); // row_ror:4
    v += t;
    t = __builtin_bit_cast(float, __builtin_amdgcn_update_dpp(
            0, __builtin_bit_cast(int, v), 0x128, 0xf, 0xf, true)); // row_ror:8
    v += t;
    return v;
}

// Wave-independent design (math validated R4/R6), register-feasible envelope:
//   - W (bf16, XOR-swizzled, 128 KB) in LDS, shared read-only by all 8 waves.
//   - Each wave owns ONE n-row end-to-end (4 chunks x 16 words): softmax denom
//     is wave-local (DPP row sums) -> ZERO barriers in the main loop; the 2
//     waves/SIMD drift into different phases and cover each other's latency.
//   - x staged in KT-HALVES (32 regs in flight, not 64 - R6's spill source);
//     each half's HBM latency hides under the other half's GEMM.
//   - x for the final multiply recovered in D-layout via identity-MFMA.
// Budget: arch ~155 VGPR + acc[16] in AGPR -> ~220 unified < 256 cap (2 w/SIMD).
__global__ __launch_bounds__(512, 2) void attend_fused(
    const float* __restrict__ x, const float* __restrict__ W,
    const float* __restrict__ bias, const float* __restrict__ ctx,
    float* __restrict__ out)
{
    __shared__ unsigned short Wb[256 * 256];   // 128 KB, [col][k] bf16, swizzled

    const int tid  = threadIdx.x;
    const int wave = tid >> 6;    // 0..7
    const int lane = tid & 63;
    const int q    = lane >> 4;   // quad 0..3
    const int c    = lane & 15;
    const int n    = blockIdx.x * 8 + wave;
    const float* xn = x + (size_t)n * (64 * 256);

    // ---- issue chunk-0 half-0 (kt 0..3) x loads first; lands under W staging.
    // A-frag layout: lane (c,q) holds x[word c][k = kt*32 + q*8 + j]
    float4v st[8];                // 32 VGPR staging (one kt-half of 16 rows)
    {
        const float* xr = xn + c * 256 + q * 8;
#pragma unroll
        for (int k2 = 0; k2 < 4; ++k2) {
            st[2 * k2]     = *(const float4v*)(xr + k2 * 32);
            st[2 * k2 + 1] = *(const float4v*)(xr + k2 * 32 + 4);
        }
    }

    // ---- stage W (f32 -> bf16) into swizzled LDS; W is L2/L3-resident ----
    {
        char* wbb = (char*)Wb;
#pragma unroll 4
        for (int i = 0; i < 32; ++i) {
            const int f4  = tid + 512 * i;        // 0..16383 float4 chunks
            const int col = f4 >> 6;              // W output-col (0..255)
            const int k4  = (f4 & 63) * 4;        // k position (floats)
            float4v v = *((const float4v*)W + f4);
            uint2 u;
            u.x = pk_bf16(v.x, v.y);
            u.y = pk_bf16(v.z, v.w);
            const int byte = (col * 512 + k4 * 2) ^ ((col & 7) << 4);  // T2 swizzle
            *(uint2*)(wbb + byte) = u;
        }
    }

    // ---- per-lane epilogue constants: hid col = nt*16 + c ----
    // e^(ctx*tanh(y)) = 2^(f*(1 - 2/(E+1))),  f = ctx*log2e,  E = 2^(2y*log2e)
    float bias16[16], f216[16];
#pragma unroll
    for (int nt = 0; nt < 16; ++nt) {
        const int o = nt * 16 + c;
        bias16[nt] = bias[o];
        f216[nt]  = ctx[o] * 1.4426950408889634f;
    }

    // ---- identity B-fragments: mfma(xfrag[nt>>1], ifr[nt&1]) = x in D-layout
    // I[k][col] = 1 iff k == p*16 + col ; lane holds B[k=q*8+j][col=c]
    short8 ifr[2];
#pragma unroll
    for (int p = 0; p < 2; ++p) {
        short8 f = (short8){0, 0, 0, 0, 0, 0, 0, 0};
#pragma unroll
        for (int j = 0; j < 8; ++j)
            f[j] = (q * 8 + j == p * 16 + c) ? (short)0x3F80 : (short)0;
        ifr[p] = f;
    }

    // ---- loop-invariant swizzled read bases: XOR over FULL k-offset (R3 fix)
    int swzbase[8];
#pragma unroll
    for (int kt = 0; kt < 8; ++kt)
        swzbase[kt] = c * 512 + ((kt * 64 + q * 16) ^ ((c & 7) << 4));

    __syncthreads();   // the ONLY block barrier: Wb ready

    const char* wbb = (const char*)Wb;

    float oacc[16];
#pragma unroll
    for (int nt = 0; nt < 16; ++nt) oacc[nt] = 0.f;

#pragma unroll 1
    for (int ch = 0; ch < 4; ++ch) {   // 4 chunks x 16 words = 64 words
        const float* xr = xn + (ch * 16 + c) * 256 + q * 8;
        short8 xfrag[8];

        // ---- cvt half-0 (kt 0..3); compiler's vmcnt wait for st lands here ----
#pragma unroll
        for (int k2 = 0; k2 < 4; ++k2) {
            uint4v u = { pk_bf16(st[2 * k2].x,     st[2 * k2].y),
                         pk_bf16(st[2 * k2].z,     st[2 * k2].w),
                         pk_bf16(st[2 * k2 + 1].x, st[2 * k2 + 1].y),
                         pk_bf16(st[2 * k2 + 1].z, st[2 * k2 + 1].w) };
            xfrag[k2] = __builtin_bit_cast(short8, u);
        }
        // ---- issue half-1 (kt 4..7): flies under GEMM half-0 ----
#pragma unroll
        for (int k2 = 0; k2 < 4; ++k2) {
            st[2 * k2]     = *(const float4v*)(xr + (k2 + 4) * 32);
            st[2 * k2 + 1] = *(const float4v*)(xr + (k2 + 4) * 32 + 4);
        }

        // ---- GEMM half-0: kt 0..3 x 256 cols, B from swizzled LDS ----
        float4v acc[16];
#pragma unroll
        for (int nt = 0; nt < 16; ++nt) acc[nt] = (float4v){0.f, 0.f, 0.f, 0.f};
#pragma unroll
        for (int kt = 0; kt < 4; ++kt) {
#pragma unroll
            for (int nt = 0; nt < 16; ++nt) {
                const short8 b = *(const short8*)(wbb + (swzbase[kt] + nt * 8192));
                acc[nt] = __builtin_amdgcn_mfma_f32_16x16x32_bf16(
                    xfrag[kt], b, acc[nt], 0, 0, 0);
            }
        }

        // ---- cvt half-1 (kt 4..7) ----
#pragma unroll
        for (int k2 = 0; k2 < 4; ++k2) {
            uint4v u = { pk_bf16(st[2 * k2].x,     st[2 * k2].y),
                         pk_bf16(st[2 * k2].z,     st[2 * k2].w),
                         pk_bf16(st[2 * k2 + 1].x, st[2 * k2 + 1].y),
                         pk_bf16(st[2 * k2 + 1].z, st[2 * k2 + 1].w) };
            xfrag[4 + k2] = __builtin_bit_cast(short8, u);
        }
        // ---- issue chunk ch+1 half-0: flies under GEMM half-1 + epilogue ----
        if (ch < 3) {
            const float* xr2 = xn + ((ch + 1) * 16 + c) * 256 + q * 8;
#pragma unroll
            for (int k2 = 0; k2 < 4; ++k2) {
                st[2 * k2]     = *(const float4v*)(xr2 + k2 * 32);
                st[2 * k2 + 1] = *(const float4v*)(xr2 + k2 * 32 + 4);
            }
        }

        // ---- GEMM half-1: kt 4..7 ----
#pragma unroll
        for (int kt = 4; kt < 8; ++kt) {
#pragma unroll
            for (int nt = 0; nt < 16; ++nt) {
                const short8 b = *(const short8*)(wbb + (swzbase[kt] + nt * 8192));
                acc[nt] = __builtin_amdgcn_mfma_f32_16x16x32_bf16(
                    xfrag[kt], b, acc[nt], 0, 0, 0);
            }
        }

        // ---- epilogue: e = 2^(f*(1-2/(E+1))); D[word=q*4+r][hid=nt*16+c] ----
        float psum[4] = {0.f, 0.f, 0.f, 0.f};
#pragma unroll
        for (int nt = 0; nt < 16; ++nt) {
#pragma unroll
            for (int r = 0; r < 4; ++r) {
                const float y  = acc[nt][r] + bias16[nt];
                const float E  = __builtin_amdgcn_exp2f(y * 2.8853900817779268f);
                const float rd = __builtin_amdgcn_rcpf(E + 1.0f);
                const float t  = __builtin_fmaf(-2.0f, rd, 1.0f);   // tanh(y)
                const float e  = __builtin_amdgcn_exp2f(f216[nt] * t);
                acc[nt][r] = e;
                psum[r] += e;
            }
        }
        // ---- wave-local softmax denominators: DPP sum over the 16 c-lanes ----
        float rinv[4];
#pragma unroll
        for (int r = 0; r < 4; ++r)
            rinv[r] = __builtin_amdgcn_rcpf(row16_sum(psum[r]));

        // ---- final: out += x*e*rinv; x recovered in D-layout via identity MFMA
        const float4v zero4 = {0.f, 0.f, 0.f, 0.f};
#pragma unroll
        for (int nt = 0; nt < 16; ++nt) {
            float4v xD = __builtin_amdgcn_mfma_f32_16x16x32_bf16(
                xfrag[nt >> 1], ifr[nt & 1], zero4, 0, 0, 0);
#pragma unroll
            for (int r = 0; r < 4; ++r)
                oacc[nt] += xD[r] * (acc[nt][r] * rinv[r]);
        }
    }

    // ---- cross-q reduce (words are split across q-groups) + store ----
#pragma unroll
    for (int nt = 0; nt < 16; ++nt) {
        float v = oacc[nt];
        v += __shfl_xor(v, 16);
        v += __shfl_xor(v, 32);
        oacc[nt] = v;
    }
    if (q == 0) {
#pragma unroll
        for (int nt = 0; nt < 16; ++nt)
            out[(size_t)n * HID + nt * 16 + c] = oacc[nt];
    }
}

extern "C" void kernel_launch(void* const* d_in, const int* in_sizes, int n_in,
                              void* d_out, int out_size, void* d_ws, size_t ws_size,
                              hipStream_t stream) {
    const float* x    = (const float*)d_in[0];   // [2048, 64, 256] f32
    const float* W    = (const float*)d_in[1];   // [256, 256] f32
    const float* bias = (const float*)d_in[2];   // [256]
    const float* ctx  = (const float*)d_in[3];   // [256]
    (void)in_sizes; (void)n_in; (void)d_ws; (void)ws_size;

    attend_fused<<<GRID, 512, 0, stream>>>(x, W, bias, ctx, (float*)d_out);
}

// Round 9
// 212.436 us; speedup vs baseline: 2.1068x; 2.1068x over previous
//
#include <hip/hip_runtime.h>
#include <hip/hip_bf16.h>

#define HID 256
#define NROWS 2048
#define GRID (NROWS / 8)        // 256 blocks x 512 threads; 8 waves, 1 n-row/wave

typedef __attribute__((ext_vector_type(8))) short short8;   // 8 bf16 (MFMA A/B frag)
typedef __attribute__((ext_vector_type(4))) float float4v;
typedef __attribute__((ext_vector_type(4))) unsigned int uint4v;

__device__ __forceinline__ unsigned int pk_bf16(float a, float b) {
    __hip_bfloat162 p = __float22bfloat162_rn(float2{a, b});  // v_cvt_pk_bf16_f32
    return *(unsigned int*)&p;
}

// sum across each 16-lane DPP row (VALU pipe, no LDS)
__device__ __forceinline__ float row16_sum(float v) {
    float t;
    t = __builtin_bit_cast(float, __builtin_amdgcn_update_dpp(
            0, __builtin_bit_cast(int, v), 0xB1, 0xf, 0xf, true));  // quad_perm(1,0,3,2)
    v += t;
    t = __builtin_bit_cast(float, __builtin_amdgcn_update_dpp(
            0, __builtin_bit_cast(int, v), 0x4E, 0xf, 0xf, true));  // quad_perm(2,3,0,1)
    v += t;
    t = __builtin_bit_cast(float, __builtin_amdgcn_update_dpp(
            0, __builtin_bit_cast(int, v), 0x124, 0xf, 0xf, true)); // row_ror:4
    v += t;
    t = __builtin_bit_cast(float, __builtin_amdgcn_update_dpp(
            0, __builtin_bit_cast(int, v), 0x128, 0xf, 0xf, true)); // row_ror:8
    v += t;
    return v;
}

// Wave-independent design (math validated R4/R6/R8: absmax 4.88e-4), with the
// register envelope finally matched to HW evidence:
//   * launch_bounds 2nd arg is MIN BLOCKS/CU (CUDA semantics — R4/R8 measured
//     (512,2)->128 regs, R6 (256,1)->256): use (512,1) -> 8 waves/CU = 2/EU
//     -> 256-reg cap, TLP preserved.
//   * bias/ctx epilogue constants live in LDS tables (frees 32 arch VGPRs);
//     a memory-clobber asm at chunk-loop top stops them being hoisted back
//     into loop-carried registers.
//   * x staged in kt-halves (32 regs in flight); each half's HBM latency
//     hides under the other half's GEMM.
//   * W (bf16, XOR-swizzled, 128 KB) in LDS shared by all 8 waves; each wave
//     owns ONE n-row end-to-end -> softmax denom is wave-local (DPP row sums)
//     -> ZERO barriers in the main loop.
// Budget: ~117 arch + 64 acc(AGPR-eligible) ~= 181 unified < 256 cap.
__global__ __launch_bounds__(512, 1) void attend_fused(
    const float* __restrict__ x, const float* __restrict__ W,
    const float* __restrict__ bias, const float* __restrict__ ctx,
    float* __restrict__ out)
{
    __shared__ unsigned short Wb[256 * 256];   // 128 KB, [col][k] bf16, swizzled
    __shared__ float btab[256];                // bias
    __shared__ float ftab[256];                // ctx * log2e

    const int tid  = threadIdx.x;
    const int wave = tid >> 6;    // 0..7
    const int lane = tid & 63;
    const int q    = lane >> 4;   // quad 0..3
    const int c    = lane & 15;
    const int n    = blockIdx.x * 8 + wave;
    const float* xn = x + (size_t)n * (64 * 256);

    // ---- issue chunk-0 half-0 (kt 0..3) x loads first; lands under W staging.
    // A-frag layout: lane (c,q) holds x[word c][k = kt*32 + q*8 + j]
    float4v st[8];                // 32 VGPR staging (one kt-half of 16 rows)
    {
        const float* xr = xn + c * 256 + q * 8;
#pragma unroll
        for (int k2 = 0; k2 < 4; ++k2) {
            st[2 * k2]     = *(const float4v*)(xr + k2 * 32);
            st[2 * k2 + 1] = *(const float4v*)(xr + k2 * 32 + 4);
        }
    }

    // ---- stage W (f32 -> bf16) into swizzled LDS; W is L2/L3-resident ----
    {
        char* wbb = (char*)Wb;
#pragma unroll 4
        for (int i = 0; i < 32; ++i) {
            const int f4  = tid + 512 * i;        // 0..16383 float4 chunks
            const int col = f4 >> 6;              // W output-col (0..255)
            const int k4  = (f4 & 63) * 4;        // k position (floats)
            float4v v = *((const float4v*)W + f4);
            uint2 u;
            u.x = pk_bf16(v.x, v.y);
            u.y = pk_bf16(v.z, v.w);
            const int byte = (col * 512 + k4 * 2) ^ ((col & 7) << 4);  // T2 swizzle
            *(uint2*)(wbb + byte) = u;
        }
        if (tid < 256) {
            btab[tid] = bias[tid];
            ftab[tid] = ctx[tid] * 1.4426950408889634f;
        }
    }

    // ---- identity B-fragments: mfma(xfrag[nt>>1], ifr[nt&1]) = x in D-layout
    // I[k][col] = 1 iff k == p*16 + col ; lane holds B[k=q*8+j][col=c]
    short8 ifr[2];
#pragma unroll
    for (int p = 0; p < 2; ++p) {
        short8 f = (short8){0, 0, 0, 0, 0, 0, 0, 0};
#pragma unroll
        for (int j = 0; j < 8; ++j)
            f[j] = (q * 8 + j == p * 16 + c) ? (short)0x3F80 : (short)0;
        ifr[p] = f;
    }

    // ---- loop-invariant swizzled read bases: XOR over FULL k-offset (R3 fix)
    int swzbase[8];
#pragma unroll
    for (int kt = 0; kt < 8; ++kt)
        swzbase[kt] = c * 512 + ((kt * 64 + q * 16) ^ ((c & 7) << 4));

    __syncthreads();   // the ONLY block barrier: Wb/btab/ftab ready

    const char* wbb = (const char*)Wb;

    float oacc[16];
#pragma unroll
    for (int nt = 0; nt < 16; ++nt) oacc[nt] = 0.f;

#pragma unroll 1
    for (int ch = 0; ch < 4; ++ch) {   // 4 chunks x 16 words = 64 words
        // Memory clobber: forces btab/ftab re-reads each iteration (keeps them
        // OUT of loop-carried regs) and anchors previously-issued prefetch
        // loads before this point (loads cannot sink past a potential store).
        asm volatile("" ::: "memory");

        const float* xr = xn + (ch * 16 + c) * 256 + q * 8;
        short8 xfrag[8];

        // ---- cvt half-0 (kt 0..3); compiler's vmcnt wait for st lands here ----
#pragma unroll
        for (int k2 = 0; k2 < 4; ++k2) {
            uint4v u = { pk_bf16(st[2 * k2].x,     st[2 * k2].y),
                         pk_bf16(st[2 * k2].z,     st[2 * k2].w),
                         pk_bf16(st[2 * k2 + 1].x, st[2 * k2 + 1].y),
                         pk_bf16(st[2 * k2 + 1].z, st[2 * k2 + 1].w) };
            xfrag[k2] = __builtin_bit_cast(short8, u);
        }
        // ---- issue half-1 (kt 4..7): flies under GEMM half-0 ----
#pragma unroll
        for (int k2 = 0; k2 < 4; ++k2) {
            st[2 * k2]     = *(const float4v*)(xr + (k2 + 4) * 32);
            st[2 * k2 + 1] = *(const float4v*)(xr + (k2 + 4) * 32 + 4);
        }

        // ---- GEMM half-0: kt 0..3 x 256 cols, B from swizzled LDS ----
        float4v acc[16];
#pragma unroll
        for (int nt = 0; nt < 16; ++nt) acc[nt] = (float4v){0.f, 0.f, 0.f, 0.f};
#pragma unroll
        for (int kt = 0; kt < 4; ++kt) {
#pragma unroll
            for (int nt = 0; nt < 16; ++nt) {
                const short8 b = *(const short8*)(wbb + (swzbase[kt] + nt * 8192));
                acc[nt] = __builtin_amdgcn_mfma_f32_16x16x32_bf16(
                    xfrag[kt], b, acc[nt], 0, 0, 0);
            }
        }

        // ---- cvt half-1 (kt 4..7) ----
#pragma unroll
        for (int k2 = 0; k2 < 4; ++k2) {
            uint4v u = { pk_bf16(st[2 * k2].x,     st[2 * k2].y),
                         pk_bf16(st[2 * k2].z,     st[2 * k2].w),
                         pk_bf16(st[2 * k2 + 1].x, st[2 * k2 + 1].y),
                         pk_bf16(st[2 * k2 + 1].z, st[2 * k2 + 1].w) };
            xfrag[4 + k2] = __builtin_bit_cast(short8, u);
        }
        // ---- issue chunk ch+1 half-0: flies under GEMM half-1 + epilogue ----
        if (ch < 3) {
            const float* xr2 = xn + ((ch + 1) * 16 + c) * 256 + q * 8;
#pragma unroll
            for (int k2 = 0; k2 < 4; ++k2) {
                st[2 * k2]     = *(const float4v*)(xr2 + k2 * 32);
                st[2 * k2 + 1] = *(const float4v*)(xr2 + k2 * 32 + 4);
            }
        }

        // ---- GEMM half-1: kt 4..7 ----
#pragma unroll
        for (int kt = 4; kt < 8; ++kt) {
#pragma unroll
            for (int nt = 0; nt < 16; ++nt) {
                const short8 b = *(const short8*)(wbb + (swzbase[kt] + nt * 8192));
                acc[nt] = __builtin_amdgcn_mfma_f32_16x16x32_bf16(
                    xfrag[kt], b, acc[nt], 0, 0, 0);
            }
        }

        // ---- epilogue: e = 2^(f*(1-2/(E+1))); D[word=q*4+r][hid=nt*16+c] ----
        // bias/f2 come from LDS per iteration (not loop-carried registers)
        float psum[4] = {0.f, 0.f, 0.f, 0.f};
#pragma unroll
        for (int nt = 0; nt < 16; ++nt) {
            const float bb = btab[nt * 16 + c];
            const float ff = ftab[nt * 16 + c];
#pragma unroll
            for (int r = 0; r < 4; ++r) {
                const float y  = acc[nt][r] + bb;
                const float E  = __builtin_amdgcn_exp2f(y * 2.8853900817779268f);
                const float rd = __builtin_amdgcn_rcpf(E + 1.0f);
                const float t  = __builtin_fmaf(-2.0f, rd, 1.0f);   // tanh(y)
                const float e  = __builtin_amdgcn_exp2f(ff * t);
                acc[nt][r] = e;
                psum[r] += e;
            }
        }
        // ---- wave-local softmax denominators: DPP sum over the 16 c-lanes ----
        float rinv[4];
#pragma unroll
        for (int r = 0; r < 4; ++r)
            rinv[r] = __builtin_amdgcn_rcpf(row16_sum(psum[r]));

        // ---- final: out += x*e*rinv; x recovered in D-layout via identity MFMA
        const float4v zero4 = {0.f, 0.f, 0.f, 0.f};
#pragma unroll
        for (int nt = 0; nt < 16; ++nt) {
            float4v xD = __builtin_amdgcn_mfma_f32_16x16x32_bf16(
                xfrag[nt >> 1], ifr[nt & 1], zero4, 0, 0, 0);
#pragma unroll
            for (int r = 0; r < 4; ++r)
                oacc[nt] += xD[r] * (acc[nt][r] * rinv[r]);
        }
    }

    // ---- cross-q reduce (words are split across q-groups) + store ----
#pragma unroll
    for (int nt = 0; nt < 16; ++nt) {
        float v = oacc[nt];
        v += __shfl_xor(v, 16);
        v += __shfl_xor(v, 32);
        oacc[nt] = v;
    }
    if (q == 0) {
#pragma unroll
        for (int nt = 0; nt < 16; ++nt)
            out[(size_t)n * HID + nt * 16 + c] = oacc[nt];
    }
}

extern "C" void kernel_launch(void* const* d_in, const int* in_sizes, int n_in,
                              void* d_out, int out_size, void* d_ws, size_t ws_size,
                              hipStream_t stream) {
    const float* x    = (const float*)d_in[0];   // [2048, 64, 256] f32
    const float* W    = (const float*)d_in[1];   // [256, 256] f32
    const float* bias = (const float*)d_in[2];   // [256]
    const float* ctx  = (const float*)d_in[3];   // [256]
    (void)in_sizes; (void)n_in; (void)d_ws; (void)ws_size;

    attend_fused<<<GRID, 512, 0, stream>>>(x, W, bias, ctx, (float*)d_out);
}